// Round 6
// baseline (1321.308 us; speedup 1.0000x reference)
//
#include <hip/hip_runtime.h>
#include <hip/hip_bf16.h>
#include <stdint.h>

// ---------------------------------------------------------------------------
// TopKAutoEncoder forward, MI355X.
// acts = (x - pre_bias) @ W_enc + latent_bias   [16384 x 4096]
// top-64/row (exact selection vs ref), relu, @ W_dec + pre_bias.
//
// R6 GEMM: 256x128 tile, 8 waves of 64x64, mfma_f32_32x32x16_f16 (2495 TF
// ceiling shape), 3-buffer LDS pipeline (72KB -> 2 blocks/CU for cross-block
// overlap), counted vmcnt(3), chunk-XOR swizzle, XCD block swizzle, setprio.
// Exact-64th-value binary search -> certain / ambiguous (margin 0.25).
// fp64 rescue of ambiguous zone (fast-path resolved in classify).
// bf16 sparse reconstruct with XCD-L2-resident W_dec slabs.
// ---------------------------------------------------------------------------

typedef _Float16 half8 __attribute__((ext_vector_type(8)));
typedef float f32x4 __attribute__((ext_vector_type(4)));
typedef float f32x16 __attribute__((ext_vector_type(16)));
typedef unsigned short ushort8 __attribute__((ext_vector_type(8)));

#define B_ROWS 16384
#define D_DIM  4096
#define TOPK   64
#define MARGIN 0.25f
#define NTILES (D_DIM / 32)

__device__ __forceinline__ void gload_lds16(const void* g, void* l) {
  __builtin_amdgcn_global_load_lds(
      (const __attribute__((address_space(1))) unsigned int*)g,
      (__attribute__((address_space(3))) unsigned int*)l, 16, 0, 0);
}

__device__ __forceinline__ unsigned f32_sortable(float f) {
  unsigned u = __float_as_uint(f);
  return (u & 0x80000000u) ? ~u : (u | 0x80000000u);
}
__device__ __forceinline__ float sortable_f32(unsigned u) {
  return __uint_as_float((u & 0x80000000u) ? (u & 0x7fffffffu) : ~u);
}
__device__ __forceinline__ unsigned short f2bf(float f) {
  unsigned u = __float_as_uint(f);
  unsigned r = (u + 0x7fffu + ((u >> 16) & 1u)) >> 16;
  return (unsigned short)r;
}

// --------------------------- conversion kernels ----------------------------

__global__ __launch_bounds__(256) void conv_x(
    const float* __restrict__ x, const float* __restrict__ pre_bias,
    _Float16* __restrict__ Xh) {
  size_t g = ((size_t)blockIdx.x * 256 + threadIdx.x) * 8;
  int col = (int)(g & (D_DIM - 1));
  float4 a = *(const float4*)(x + g);
  float4 b = *(const float4*)(x + g + 4);
  float4 p = *(const float4*)(pre_bias + col);
  float4 q = *(const float4*)(pre_bias + col + 4);
  half8 h;
  h[0] = (_Float16)(a.x - p.x); h[1] = (_Float16)(a.y - p.y);
  h[2] = (_Float16)(a.z - p.z); h[3] = (_Float16)(a.w - p.w);
  h[4] = (_Float16)(b.x - q.x); h[5] = (_Float16)(b.y - q.y);
  h[6] = (_Float16)(b.z - q.z); h[7] = (_Float16)(b.w - q.w);
  *(half8*)(Xh + g) = h;
}

// W_enc [K][N] fp32 -> WhT [N][K] fp16  AND WT [N][K] fp32 (for fp64 rescue)
__global__ __launch_bounds__(256) void transp_w(
    const float* __restrict__ W, _Float16* __restrict__ WhT,
    float* __restrict__ WT) {
  __shared__ float tile[64][65];
  int bx = blockIdx.x, by = blockIdx.y;
  int tx = threadIdx.x & 63, ty4 = threadIdx.x >> 6;
  #pragma unroll 4
  for (int i = 0; i < 16; ++i) {
    int r = ty4 * 16 + i;
    tile[r][tx] = W[(size_t)(by * 64 + r) * D_DIM + bx * 64 + tx];
  }
  __syncthreads();
  #pragma unroll 4
  for (int i = 0; i < 16; ++i) {
    int r = ty4 * 16 + i;
    float v = tile[tx][r];
    size_t o = (size_t)(bx * 64 + r) * D_DIM + by * 64 + tx;
    WT[o] = v;
    WhT[o] = (_Float16)v;
  }
}

__global__ __launch_bounds__(256) void conv_wd(
    const float* __restrict__ W, unsigned short* __restrict__ o) {
  size_t g = ((size_t)blockIdx.x * 256 + threadIdx.x) * 8;
  float4 a = *(const float4*)(W + g);
  float4 b = *(const float4*)(W + g + 4);
  ushort8 v;
  v[0] = f2bf(a.x); v[1] = f2bf(a.y); v[2] = f2bf(a.z); v[3] = f2bf(a.w);
  v[4] = f2bf(b.x); v[5] = f2bf(b.y); v[6] = f2bf(b.z); v[7] = f2bf(b.w);
  *(ushort8*)(o + g) = v;
}

// ------------------------------- fp16 GEMM ---------------------------------
// 256x128 tile, BK=32, 512 threads (8 waves = 4M x 2N, 64x64 out each).
// LDS: 3 bufs x (A 16KB + B 8KB) = 72KB -> 2 blocks/CU.
// Body t: stage tile t+2 into buf (t+2)%3 (its last readers finished at the
// barrier ending body t-1); read frags of tile t from buf t%3; 8 MFMA
// 32x32x16; vmcnt(3) (tile t+1's 3 loads complete, t+2's stay in flight);
// barrier. Prologue: stage 0,1; vmcnt(3); BARRIER (cross-wave visibility --
// vmcnt is per-wave only, R4 lesson).
// Chunk-XOR swizzle: physical chunk p holds logical p ^ ((p>>3)&3); read of
// logical chunk c of row r at phys c ^ ((r>>1)&3). 32x32 frag read: each
// 16-lane quarter covers all 8 bank groups exactly 2x (free).

#define STAGE3(KK, BS)                                                         \
  do {                                                                         \
    gload_lds16(aSrc0 + (KK), lds + (BS) + dA0);                               \
    gload_lds16(aSrc1 + (KK), lds + (BS) + dA1);                               \
    gload_lds16(bSrc + (KK), lds + (BS) + dB);                                 \
  } while (0)

#define GBODY(DOSTAGE, KK, VMSTR)                                              \
  do {                                                                         \
    if (DOSTAGE) STAGE3((KK), boffS);                                          \
    _Pragma("unroll") for (int ks = 0; ks < 2; ++ks) {                         \
      const int kx = ks * 16; /* (chunk^2)*8 == off^16 */                      \
      half8 a0 = *(const half8*)(lds + boffC + (aOff ^ kx));                   \
      half8 a1 = *(const half8*)(lds + boffC + (aOff ^ kx) + 1024);            \
      half8 b0 = *(const half8*)(lds + boffC + (bOff ^ kx));                   \
      half8 b1 = *(const half8*)(lds + boffC + (bOff ^ kx) + 1024);            \
      __builtin_amdgcn_s_setprio(1);                                           \
      acc00 = __builtin_amdgcn_mfma_f32_32x32x16_f16(a0, b0, acc00, 0, 0, 0);  \
      acc01 = __builtin_amdgcn_mfma_f32_32x32x16_f16(a0, b1, acc01, 0, 0, 0);  \
      acc10 = __builtin_amdgcn_mfma_f32_32x32x16_f16(a1, b0, acc10, 0, 0, 0);  \
      acc11 = __builtin_amdgcn_mfma_f32_32x32x16_f16(a1, b1, acc11, 0, 0, 0);  \
      __builtin_amdgcn_s_setprio(0);                                           \
    }                                                                          \
    asm volatile("s_waitcnt " VMSTR ::: "memory");                             \
    __builtin_amdgcn_s_barrier();                                              \
    asm volatile("" ::: "memory");                                             \
  } while (0)

#define GROT()                                                                 \
  do {                                                                         \
    boffC += 12288; if (boffC == 36864) boffC = 0;                             \
    boffS += 12288; if (boffS == 36864) boffS = 0;                             \
  } while (0)

__global__ __launch_bounds__(512, 4) void gemm_f16(
    const _Float16* __restrict__ A, const _Float16* __restrict__ Bt,
    const float* __restrict__ latent_bias, float* __restrict__ C) {
  extern __shared__ _Float16 lds[];
  const int tid = threadIdx.x;
  const int lane = tid & 63, l31 = lane & 31, lhi = lane >> 5;
  const int wave = tid >> 6, wvm = wave & 3, wvn = wave >> 2;

  // XCD swizzle; grid = 64*32 = 2048, divisible by 8 -> bijective.
  int bid = blockIdx.x;
  int swz = (bid & 7) * (2048 >> 3) + (bid >> 3);
  const int bmBase = (swz >> 5) * 256;
  const int bnBase = (swz & 31) * 128;

  // staging: A = 1024 chunks (2/thread), B = 512 chunks (1/thread)
  const int pA0 = tid, pA1 = 512 + tid, pB = tid;
  const int sA0 = pA0 ^ ((pA0 >> 3) & 3), sA1 = pA1 ^ ((pA1 >> 3) & 3);
  const int sB = pB ^ ((pB >> 3) & 3);
  const _Float16* aSrc0 = A + (size_t)(bmBase + (sA0 >> 2)) * D_DIM + (sA0 & 3) * 8;
  const _Float16* aSrc1 = A + (size_t)(bmBase + (sA1 >> 2)) * D_DIM + (sA1 & 3) * 8;
  const _Float16* bSrc  = Bt + (size_t)(bnBase + (sB >> 2)) * D_DIM + (sB & 3) * 8;
  const int dA0 = pA0 * 8, dA1 = pA1 * 8, dB = 8192 + pB * 8;

  // fragment read offsets (halves, within a buf): A frag (mi,ks):
  // row = wvm*64 + mi*32 + l31, logical chunk = ks*2 + lhi,
  // phys = chunk ^ ((l31>>1)&3). mi -> +1024; ks -> offset^16.
  const int cp0 = lhi ^ ((l31 >> 1) & 3);
  const int aOff = (wvm * 64 + l31) * 32 + cp0 * 8;
  const int bOff = 8192 + (wvn * 64 + l31) * 32 + cp0 * 8;

  f32x16 acc00, acc01, acc10, acc11;
  #pragma unroll
  for (int i = 0; i < 16; ++i) {
    acc00[i] = 0.f; acc01[i] = 0.f; acc10[i] = 0.f; acc11[i] = 0.f;
  }

  int boffC = 0, boffS = 24576;
  STAGE3(0, 0);
  STAGE3(32, 12288);
  asm volatile("s_waitcnt vmcnt(3)" ::: "memory");
  __builtin_amdgcn_s_barrier();
  asm volatile("" ::: "memory");

  for (int t = 0; t < NTILES - 3; ++t) {       // t = 0..124, stage 2..126
    GBODY(true, (t + 2) * 32, "vmcnt(3)");
    GROT();
  }
  GBODY(true, (NTILES - 1) * 32, "vmcnt(0)");  // t=125, stage 127, drain
  GROT();
  GBODY(false, 0, "vmcnt(0)");                 // t=126
  GROT();
  GBODY(false, 0, "vmcnt(0)");                 // t=127

  // epilogue: C/D 32x32 mapping col=lane&31, row=(r&3)+8*(r>>2)+4*(lane>>5)
  const int crow0 = bmBase + wvm * 64;
  const int ccol0 = bnBase + wvn * 64;
  const float lb0 = latent_bias[ccol0 + l31];
  const float lb1 = latent_bias[ccol0 + 32 + l31];
  #pragma unroll
  for (int r = 0; r < 16; ++r) {
    const int rr = (r & 3) + 8 * (r >> 2) + 4 * lhi;
    C[(size_t)(crow0 + rr) * D_DIM + ccol0 + l31] = acc00[r] + lb0;
    C[(size_t)(crow0 + rr) * D_DIM + ccol0 + 32 + l31] = acc01[r] + lb1;
    C[(size_t)(crow0 + 32 + rr) * D_DIM + ccol0 + l31] = acc10[r] + lb0;
    C[(size_t)(crow0 + 32 + rr) * D_DIM + ccol0 + 32 + l31] = acc11[r] + lb1;
  }
}

// --------------------------- top-k classify --------------------------------
// Register-resident: each thread holds 16 values. 20-step bitwise binary
// search (bits 31..12): thr <= T64_approx < thr+2^12. Members: approx >
// Thi+MARGIN (provably in exact top-64; strictly <64 of them since
// count(>= thr+4096) < 64). Zone: [Tlo-MARGIN, Thi+MARGIN]. m+zone >= 64.
// If zone == need, zone entries are emitted directly (no rescue).

__global__ __launch_bounds__(256) void topk_classify(
    const float* __restrict__ acts, float* __restrict__ vals,
    int* __restrict__ idxs, int* __restrict__ ambIdx,
    int* __restrict__ rowMeta) {
  const int row = blockIdx.x;
  const int tid = threadIdx.x;
  const int lane = tid & 63, wave = tid >> 6;
  __shared__ int sred[4];
  const float* arow = acts + (size_t)row * D_DIM;
  unsigned su[16];
  #pragma unroll
  for (int i = 0; i < 4; ++i) {
    float4 a = *(const float4*)(arow + i * 1024 + tid * 4);
    su[4 * i + 0] = f32_sortable(a.x);
    su[4 * i + 1] = f32_sortable(a.y);
    su[4 * i + 2] = f32_sortable(a.z);
    su[4 * i + 3] = f32_sortable(a.w);
  }
  unsigned thr = 0u;
  for (int b = 31; b >= 12; --b) {
    unsigned cand = thr | (1u << b);
    int c = 0;
    #pragma unroll
    for (int i = 0; i < 16; ++i) c += (su[i] >= cand) ? 1 : 0;
    #pragma unroll
    for (int off = 32; off; off >>= 1) c += __shfl_down(c, off);
    if (lane == 0) sred[wave] = c;
    __syncthreads();
    int tot = sred[0] + sred[1] + sred[2] + sred[3];
    if (tot >= TOPK) thr = cand;
    __syncthreads();
  }
  float Tlo = sortable_f32(thr);
  float Thi = sortable_f32(thr + 4096u);
  unsigned uhi = f32_sortable(Thi + MARGIN);
  unsigned ulo = f32_sortable(Tlo - MARGIN);
  int mC = 0, aC = 0;
  #pragma unroll
  for (int i = 0; i < 16; ++i) {
    unsigned u = su[i];
    if (u > uhi) ++mC;
    else if (u >= ulo) ++aC;
  }
  int xs = mC | (aC << 16);
  #pragma unroll
  for (int off = 1; off < 64; off <<= 1) {
    int y = __shfl_up(xs, off);
    if (lane >= off) xs += y;
  }
  if (lane == 63) sred[wave] = xs;
  __syncthreads();
  int base = 0;
  for (int w = 0; w < 4; ++w)
    if (w < wave) base += sred[w];
  int tot = sred[0] + sred[1] + sred[2] + sred[3];
  int incl = base + xs;
  int mp = (incl & 0xffff) - mC;
  int ap = (incl >> 16) - aC;
  int mTot = tot & 0xffff, aTot = tot >> 16;
  const int need = TOPK - mTot;
  const bool fast = (aTot == need);  // zone exactly fills the remainder
  #pragma unroll
  for (int e = 0; e < 16; ++e) {
    unsigned u = su[e];
    int d = (e >> 2) * 1024 + tid * 4 + (e & 3);
    if (u > uhi) {
      vals[(size_t)row * TOPK + mp] = fmaxf(sortable_f32(u), 0.0f);
      idxs[(size_t)row * TOPK + mp] = d;
      ++mp;
    } else if (u >= ulo) {
      if (fast) {
        vals[(size_t)row * TOPK + mTot + ap] = fmaxf(sortable_f32(u), 0.0f);
        idxs[(size_t)row * TOPK + mTot + ap] = d;
      } else if (ap < 128) {
        ambIdx[(size_t)row * 128 + ap] = d;
      }
      ++ap;
    }
  }
  if (tid == 0) {
    rowMeta[row * 2 + 0] = mTot;
    rowMeta[row * 2 + 1] = (fast || need <= 0) ? 0 : ((aTot > 128) ? 128 : aTot);
  }
}

// ------------------------------ fp64 rescue --------------------------------

__global__ __launch_bounds__(256) void rescue(
    const float* __restrict__ x, const float* __restrict__ WT,
    const float* __restrict__ pre_bias, const float* __restrict__ latent_bias,
    const float* __restrict__ acts, const int* __restrict__ ambIdx,
    const int* __restrict__ rowMeta, float* __restrict__ vals,
    int* __restrict__ idxs) {
  const int row = blockIdx.x;
  const int m = rowMeta[row * 2 + 0];
  const int s = rowMeta[row * 2 + 1];
  const int need = TOPK - m;
  const int tid = threadIdx.x;
  if (need <= 0 || s <= 0) return;
  if (s == need) {  // residual fast path (normally resolved in classify)
    if (tid < s) {
      int d = ambIdx[(size_t)row * 128 + tid];
      float v = acts[(size_t)row * D_DIM + d];
      vals[(size_t)row * TOPK + m + tid] = fmaxf(v, 0.0f);
      idxs[(size_t)row * TOPK + m + tid] = d;
    }
    return;
  }
  __shared__ double exv[128];
  const int lane = tid & 63, wave = tid >> 6;
  const float* xr = x + (size_t)row * D_DIM;
  for (int c = wave; c < s; c += 4) {
    int d = ambIdx[(size_t)row * 128 + c];
    const float* wrow = WT + (size_t)d * D_DIM;
    double acc = 0.0;
    #pragma unroll 4
    for (int t = 0; t < 16; ++t) {
      int k0 = t * 256 + lane * 4;
      float4 xv = *(const float4*)(xr + k0);
      float4 pv = *(const float4*)(pre_bias + k0);
      float4 wv = *(const float4*)(wrow + k0);
      acc = fma((double)xv.x - (double)pv.x, (double)wv.x, acc);
      acc = fma((double)xv.y - (double)pv.y, (double)wv.y, acc);
      acc = fma((double)xv.z - (double)pv.z, (double)wv.z, acc);
      acc = fma((double)xv.w - (double)pv.w, (double)wv.w, acc);
    }
    #pragma unroll
    for (int off = 32; off; off >>= 1) acc += __shfl_down(acc, off);
    if (lane == 0) exv[c] = acc + (double)latent_bias[d];
  }
  __syncthreads();
  if (tid == 0) {
    for (int t = 0; t < need; ++t) {
      double best = -1.0e300; int besti = 1 << 30; int bestc = -1;
      for (int c = 0; c < s; ++c) {
        double v = exv[c];
        int d = ambIdx[(size_t)row * 128 + c];
        if (v > best || (v == best && d < besti)) {
          best = v; besti = d; bestc = c;
        }
      }
      vals[(size_t)row * TOPK + m + t] = fmaxf((float)best, 0.0f);
      idxs[(size_t)row * TOPK + m + t] = besti;
      exv[bestc] = -1.0e300;
    }
  }
}

// ----------------------------- reconstruct ---------------------------------

__global__ __launch_bounds__(256) void reconstruct(
    const unsigned short* __restrict__ Wd, const float* __restrict__ vals,
    const int* __restrict__ idxs, const float* __restrict__ pre_bias,
    float* __restrict__ out) {
  const int bid = blockIdx.x;
  const int cb = bid & 7, rowblk = bid >> 3;
  const int tid = threadIdx.x, lane = tid & 63, wave = tid >> 6;
  const int row = rowblk * 4 + wave;
  const int col0 = cb * 512 + lane * 8;
  __shared__ float sval[256];
  __shared__ int sidx[256];
  sval[tid] = vals[(size_t)(rowblk * 4 + (tid >> 6)) * TOPK + (tid & 63)];
  sidx[tid] = idxs[(size_t)(rowblk * 4 + (tid >> 6)) * TOPK + (tid & 63)];
  __syncthreads();
  float acc[8];
  float4 p0 = *(const float4*)(pre_bias + col0);
  float4 p1 = *(const float4*)(pre_bias + col0 + 4);
  acc[0] = p0.x; acc[1] = p0.y; acc[2] = p0.z; acc[3] = p0.w;
  acc[4] = p1.x; acc[5] = p1.y; acc[6] = p1.z; acc[7] = p1.w;
  #pragma unroll 4
  for (int k = 0; k < TOPK; ++k) {
    float v = sval[wave * 64 + k];
    int d = sidx[wave * 64 + k];
    ushort8 w = *(const ushort8*)(Wd + (size_t)d * D_DIM + col0);
    #pragma unroll
    for (int j = 0; j < 8; ++j)
      acc[j] = fmaf(v, __uint_as_float(((unsigned)w[j]) << 16), acc[j]);
  }
  float4 o0 = {acc[0], acc[1], acc[2], acc[3]};
  float4 o1 = {acc[4], acc[5], acc[6], acc[7]};
  *(float4*)(out + (size_t)row * D_DIM + col0) = o0;
  *(float4*)(out + (size_t)row * D_DIM + col0 + 4) = o1;
}

// ------------------------------- launcher ----------------------------------

extern "C" void kernel_launch(void* const* d_in, const int* in_sizes, int n_in,
                              void* d_out, int out_size, void* d_ws,
                              size_t ws_size, hipStream_t stream) {
  const float* x           = (const float*)d_in[0];
  // d_in[1] = ema_frequency_counter (unused by reference)
  const float* W_enc       = (const float*)d_in[2];
  const float* W_dec       = (const float*)d_in[3];
  const float* pre_bias    = (const float*)d_in[4];
  const float* latent_bias = (const float*)d_in[5];
  float* out = (float*)d_out;  // doubles as acts buffer, overwritten last
  char* ws = (char*)d_ws;
  size_t off = 0;
  auto alloc = [&](size_t bytes) {
    size_t o = off;
    off = (off + bytes + 255) & ~(size_t)255;
    return o;
  };
  _Float16* Xh        = (_Float16*)(ws + alloc((size_t)B_ROWS * D_DIM * 2));
  _Float16* WhT       = (_Float16*)(ws + alloc((size_t)D_DIM * D_DIM * 2));
  float* WT           = (float*)(ws + alloc((size_t)D_DIM * D_DIM * 4));
  unsigned short* Wd  = (unsigned short*)(ws + alloc((size_t)D_DIM * D_DIM * 2));
  float* vals         = (float*)(ws + alloc((size_t)B_ROWS * TOPK * 4));
  int* idxs           = (int*)(ws + alloc((size_t)B_ROWS * TOPK * 4));
  int* ambIdx         = (int*)(ws + alloc((size_t)B_ROWS * 128 * 4));
  int* rowMeta        = (int*)(ws + alloc((size_t)B_ROWS * 2 * 4));
  (void)ws_size; (void)in_sizes; (void)n_in; (void)out_size;

  // allow 72KB dynamic LDS for the GEMM (cheap, deterministic, idempotent)
  (void)hipFuncSetAttribute((const void*)gemm_f16,
                            hipFuncAttributeMaxDynamicSharedMemorySize,
                            73728);

  conv_x<<<(B_ROWS * D_DIM / 8) / 256, 256, 0, stream>>>(x, pre_bias, Xh);
  transp_w<<<dim3(D_DIM / 64, D_DIM / 64), 256, 0, stream>>>(W_enc, WhT, WT);
  conv_wd<<<((size_t)D_DIM * D_DIM / 8) / 256, 256, 0, stream>>>(W_dec, Wd);
  gemm_f16<<<(B_ROWS / 256) * (D_DIM / 128), 512, 73728, stream>>>(
      Xh, WhT, latent_bias, out);
  topk_classify<<<B_ROWS, 256, 0, stream>>>(out, vals, idxs, ambIdx, rowMeta);
  rescue<<<B_ROWS, 256, 0, stream>>>(x, WT, pre_bias, latent_bias, out,
                                     ambIdx, rowMeta, vals, idxs);
  reconstruct<<<(B_ROWS / 4) * 8, 256, 0, stream>>>(Wd, vals, idxs, pre_bias,
                                                    out);
}

// Round 7
// 1207.720 us; speedup vs baseline: 1.0941x; 1.0941x over previous
//
#include <hip/hip_runtime.h>
#include <hip/hip_bf16.h>
#include <stdint.h>

// ---------------------------------------------------------------------------
// TopKAutoEncoder forward, MI355X.
// acts = (x - pre_bias) @ W_enc + latent_bias   [16384 x 4096]
// top-64/row (exact selection vs ref), relu, @ W_dec + pre_bias.
//
// R7 GEMM: 256x256 tile, 8 waves (2M x 4N, 128x64 out each), BK=64 K-tiles,
// 2 LDS dbufs (128KB), 4 phases per K-tile:
//   ph1: ds_read A(kk0,m0-3)+B(kk0) | stage A-kh0(t+1) | bar | 16 MFMA | bar
//   ph2: ds_read A(kk0,m4-7) [B reused] | stage B-kh0(t+1) | bar | MFMA |
//        vmcnt(4) bar
//   ph3/ph4: same for kk1.
// Counted vmcnt(4) twice per K-tile (FIFO: completes exactly the two
// half-tiles the following phases read); never 0 until the last tile.
// Addressing/swizzle/epilogue identical to the verified R3 kernel
// (chunk-XOR f(row)=(row>>1)&3, 0 bank conflicts, XCD block swizzle).
// Exact-64th-value binary search -> certain / ambiguous (margin 0.25).
// fp64 rescue of ambiguous zone (fast-path resolved in classify).
// bf16 sparse reconstruct with XCD-L2-resident W_dec slabs.
// ---------------------------------------------------------------------------

typedef _Float16 half8 __attribute__((ext_vector_type(8)));
typedef float f32x4 __attribute__((ext_vector_type(4)));
typedef unsigned short ushort8 __attribute__((ext_vector_type(8)));

#define B_ROWS 16384
#define D_DIM  4096
#define TOPK   64
#define MARGIN 0.25f
#define KTILES (D_DIM / 64)

__device__ __forceinline__ void gload_lds16(const void* g, void* l) {
  __builtin_amdgcn_global_load_lds(
      (const __attribute__((address_space(1))) unsigned int*)g,
      (__attribute__((address_space(3))) unsigned int*)l, 16, 0, 0);
}

__device__ __forceinline__ unsigned f32_sortable(float f) {
  unsigned u = __float_as_uint(f);
  return (u & 0x80000000u) ? ~u : (u | 0x80000000u);
}
__device__ __forceinline__ float sortable_f32(unsigned u) {
  return __uint_as_float((u & 0x80000000u) ? (u & 0x7fffffffu) : ~u);
}
__device__ __forceinline__ unsigned short f2bf(float f) {
  unsigned u = __float_as_uint(f);
  unsigned r = (u + 0x7fffu + ((u >> 16) & 1u)) >> 16;
  return (unsigned short)r;
}

// --------------------------- conversion kernels ----------------------------

__global__ __launch_bounds__(256) void conv_x(
    const float* __restrict__ x, const float* __restrict__ pre_bias,
    _Float16* __restrict__ Xh) {
  size_t g = ((size_t)blockIdx.x * 256 + threadIdx.x) * 8;
  int col = (int)(g & (D_DIM - 1));
  float4 a = *(const float4*)(x + g);
  float4 b = *(const float4*)(x + g + 4);
  float4 p = *(const float4*)(pre_bias + col);
  float4 q = *(const float4*)(pre_bias + col + 4);
  half8 h;
  h[0] = (_Float16)(a.x - p.x); h[1] = (_Float16)(a.y - p.y);
  h[2] = (_Float16)(a.z - p.z); h[3] = (_Float16)(a.w - p.w);
  h[4] = (_Float16)(b.x - q.x); h[5] = (_Float16)(b.y - q.y);
  h[6] = (_Float16)(b.z - q.z); h[7] = (_Float16)(b.w - q.w);
  *(half8*)(Xh + g) = h;
}

// W_enc [K][N] fp32 -> WhT [N][K] fp16  AND WT [N][K] fp32 (for fp64 rescue)
__global__ __launch_bounds__(256) void transp_w(
    const float* __restrict__ W, _Float16* __restrict__ WhT,
    float* __restrict__ WT) {
  __shared__ float tile[64][65];
  int bx = blockIdx.x, by = blockIdx.y;
  int tx = threadIdx.x & 63, ty4 = threadIdx.x >> 6;
  #pragma unroll 4
  for (int i = 0; i < 16; ++i) {
    int r = ty4 * 16 + i;
    tile[r][tx] = W[(size_t)(by * 64 + r) * D_DIM + bx * 64 + tx];
  }
  __syncthreads();
  #pragma unroll 4
  for (int i = 0; i < 16; ++i) {
    int r = ty4 * 16 + i;
    float v = tile[tx][r];
    size_t o = (size_t)(bx * 64 + r) * D_DIM + by * 64 + tx;
    WT[o] = v;
    WhT[o] = (_Float16)v;
  }
}

__global__ __launch_bounds__(256) void conv_wd(
    const float* __restrict__ W, unsigned short* __restrict__ o) {
  size_t g = ((size_t)blockIdx.x * 256 + threadIdx.x) * 8;
  float4 a = *(const float4*)(W + g);
  float4 b = *(const float4*)(W + g + 4);
  ushort8 v;
  v[0] = f2bf(a.x); v[1] = f2bf(a.y); v[2] = f2bf(a.z); v[3] = f2bf(a.w);
  v[4] = f2bf(b.x); v[5] = f2bf(b.y); v[6] = f2bf(b.z); v[7] = f2bf(b.w);
  *(ushort8*)(o + g) = v;
}

// ------------------------------- fp16 GEMM ---------------------------------
// LDS layout (halves): dbuf d at d*32768:
//   A: + kh*8192 + row*32 + chunk*8     (256 rows x 4 chunks of 16B)
//   B: + 16384 + kh*8192 + row*32 + chunk*8
// Physical chunk p of row r holds logical chunk p ^ ((r>>1)&3) -> bank
// group (r&1)*4 + (c ^ f(r)) covers all 8 groups exactly 2x per 16-lane
// fragment quarter (2-way = free). Verified R3 (0 conflicts, absmax pass).
//
// Per-thread load FIFO ledger (2 loads per STG):
//   prologue: A0h0 A0h0 B0h0 B0h0 A0h1 A0h1 B0h1 B0h1; vmcnt(4) completes
//   {A0h0,B0h0}; ph1 reads them. ph1 stages A1h0 (6), ph2 stages B1h0 (8);
//   vmcnt(4) completes {A0h1,B0h1} for ph3/ph4. ph3 +A1h1 (6), ph4 +B1h1
//   (8); vmcnt(4) completes {A1h0,B1h0} for t+1 ph1. Steady state.
// Buffer overwrite: STG(t+1) writes buf (t+1)&1, whose last readers
// (tile t-1) completed their lgkm-waited MFMAs >=2 barriers earlier.

#define STG_A(T, KH)                                                           \
  do {                                                                         \
    const int ds_ = ((T) & 1) * 32768 + (KH) * 8192;                           \
    const int ko_ = (T) * 64 + (KH) * 32;                                      \
    gload_lds16(aS0 + ko_, lds + ds_ + i0 * 8);                                \
    gload_lds16(aS1 + ko_, lds + ds_ + i1 * 8);                                \
  } while (0)

#define STG_B(T, KH)                                                           \
  do {                                                                         \
    const int ds_ = ((T) & 1) * 32768 + 16384 + (KH) * 8192;                   \
    const int ko_ = (T) * 64 + (KH) * 32;                                      \
    gload_lds16(bS0 + ko_, lds + ds_ + i0 * 8);                                \
    gload_lds16(bS1 + ko_, lds + ds_ + i1 * 8);                                \
  } while (0)

#define VMW(N) asm volatile("s_waitcnt vmcnt(" #N ")" ::: "memory")
#define BARR()                                                                 \
  do {                                                                         \
    asm volatile("" ::: "memory");                                             \
    __builtin_amdgcn_s_barrier();                                              \
    asm volatile("" ::: "memory");                                             \
  } while (0)

// One phase: ds_read its fragments, issue its stage, barrier #1 (issue /
// compute split), 16 MFMA under setprio. Barrier #2 is placed by the caller
// (optionally preceded by the counted vmcnt).
#define PH(T, KK, MB, LOADB, STAGEOP)                                          \
  do {                                                                         \
    const int dC_ = ((T) & 1) * 32768 + (KK) * 8192;                           \
    half8 af_[4];                                                              \
    _Pragma("unroll") for (int mi = 0; mi < 4; ++mi)                           \
        af_[mi] = *(const half8*)(lds + dC_ + aBase + ((MB) + mi) * 512);      \
    if (LOADB) {                                                               \
      _Pragma("unroll") for (int nj = 0; nj < 4; ++nj)                         \
          bfr[nj] = *(const half8*)(lds + dC_ + 16384 + bBase + nj * 512);     \
    }                                                                          \
    STAGEOP;                                                                   \
    BARR();                                                                    \
    __builtin_amdgcn_s_setprio(1);                                             \
    _Pragma("unroll") for (int mi = 0; mi < 4; ++mi)                           \
        _Pragma("unroll") for (int nj = 0; nj < 4; ++nj)                       \
        acc[(MB) + mi][nj] = __builtin_amdgcn_mfma_f32_16x16x32_f16(           \
            af_[mi], bfr[nj], acc[(MB) + mi][nj], 0, 0, 0);                    \
    __builtin_amdgcn_s_setprio(0);                                             \
  } while (0)

__global__ __launch_bounds__(512, 2) void gemm_f16(
    const _Float16* __restrict__ A, const _Float16* __restrict__ Bt,
    const float* __restrict__ latent_bias, float* __restrict__ C) {
  extern __shared__ _Float16 lds[];
  const int tid = threadIdx.x;
  const int lane = tid & 63, wave = tid >> 6;
  const int wr = wave >> 2, wc = wave & 3;

  // XCD-aware swizzle; grid = 64*16 = 1024, divisible by 8 -> bijective.
  int bid = blockIdx.x;
  int swz = (bid & 7) * (1024 >> 3) + (bid >> 3);
  const int bmBase = (swz >> 4) * 256;
  const int bnBase = (swz & 15) * 256;

  // staging: physical slot i (of 1024 16B slots per half-tile) holds
  // logical chunk s = i ^ ((i>>3)&3)  [row = i>>2 unchanged]
  const int i0 = tid, i1 = 512 + tid;
  const int s0 = i0 ^ ((i0 >> 3) & 3), s1 = i1 ^ ((i1 >> 3) & 3);
  const _Float16* aS0 = A + (size_t)(bmBase + (s0 >> 2)) * D_DIM + (s0 & 3) * 8;
  const _Float16* aS1 = A + (size_t)(bmBase + (s1 >> 2)) * D_DIM + (s1 & 3) * 8;
  const _Float16* bS0 = Bt + (size_t)(bnBase + (s0 >> 2)) * D_DIM + (s0 & 3) * 8;
  const _Float16* bS1 = Bt + (size_t)(bnBase + (s1 >> 2)) * D_DIM + (s1 & 3) * 8;

  // fragment reads: logical chunk c of row r at phys c ^ ((r>>1)&3)
  const int fr = lane & 15, c4 = lane >> 4;
  const int swzc = (c4 ^ ((fr >> 1) & 3)) * 8;
  const int aBase = (wr * 128 + fr) * 32 + swzc;
  const int bBase = (wc * 64 + fr) * 32 + swzc;

  f32x4 acc[8][4];
  #pragma unroll
  for (int i = 0; i < 8; ++i)
    #pragma unroll
    for (int j = 0; j < 4; ++j) acc[i][j] = f32x4{0.f, 0.f, 0.f, 0.f};
  half8 bfr[4];

  // prologue: stage tile 0 (order Ah0 Bh0 Ah1 Bh1); wait the first two
  // half-tiles; barrier before any cross-wave LDS read (R4 lesson).
  STG_A(0, 0); STG_B(0, 0); STG_A(0, 1); STG_B(0, 1);
  VMW(4);
  BARR();

  for (int t = 0; t < KTILES - 1; ++t) {
    PH(t, 0, 0, true,  STG_A(t + 1, 0));
    BARR();
    PH(t, 0, 4, false, STG_B(t + 1, 0));
    VMW(4); BARR();
    PH(t, 1, 0, true,  STG_A(t + 1, 1));
    BARR();
    PH(t, 1, 4, false, STG_B(t + 1, 1));
    VMW(4); BARR();
  }
  // t = KTILES-1: no staging; drain kh1 loads before ph3.
  PH(KTILES - 1, 0, 0, true,  (void)0);
  BARR();
  PH(KTILES - 1, 0, 4, false, (void)0);
  VMW(0); BARR();
  PH(KTILES - 1, 1, 0, true,  (void)0);
  BARR();
  PH(KTILES - 1, 1, 4, false, (void)0);

  // epilogue (verified R3 C/D mapping)
  const int crow0 = bmBase + wr * 128 + c4 * 4;
  const int ccol0 = bnBase + wc * 64 + fr;
  #pragma unroll
  for (int mi = 0; mi < 8; ++mi)
    #pragma unroll
    for (int nj = 0; nj < 4; ++nj) {
      int col = ccol0 + nj * 16;
      float lb = latent_bias[col];
      #pragma unroll
      for (int r = 0; r < 4; ++r)
        C[(size_t)(crow0 + mi * 16 + r) * D_DIM + col] = acc[mi][nj][r] + lb;
    }
}

// --------------------------- top-k classify --------------------------------

__global__ __launch_bounds__(256) void topk_classify(
    const float* __restrict__ acts, float* __restrict__ vals,
    int* __restrict__ idxs, int* __restrict__ ambIdx,
    int* __restrict__ rowMeta) {
  const int row = blockIdx.x;
  const int tid = threadIdx.x;
  const int lane = tid & 63, wave = tid >> 6;
  __shared__ int sred[4];
  const float* arow = acts + (size_t)row * D_DIM;
  unsigned su[16];
  #pragma unroll
  for (int i = 0; i < 4; ++i) {
    float4 a = *(const float4*)(arow + i * 1024 + tid * 4);
    su[4 * i + 0] = f32_sortable(a.x);
    su[4 * i + 1] = f32_sortable(a.y);
    su[4 * i + 2] = f32_sortable(a.z);
    su[4 * i + 3] = f32_sortable(a.w);
  }
  unsigned thr = 0u;
  for (int b = 31; b >= 12; --b) {
    unsigned cand = thr | (1u << b);
    int c = 0;
    #pragma unroll
    for (int i = 0; i < 16; ++i) c += (su[i] >= cand) ? 1 : 0;
    #pragma unroll
    for (int off = 32; off; off >>= 1) c += __shfl_down(c, off);
    if (lane == 0) sred[wave] = c;
    __syncthreads();
    int tot = sred[0] + sred[1] + sred[2] + sred[3];
    if (tot >= TOPK) thr = cand;
    __syncthreads();
  }
  float Tlo = sortable_f32(thr);
  float Thi = sortable_f32(thr + 4096u);
  unsigned uhi = f32_sortable(Thi + MARGIN);
  unsigned ulo = f32_sortable(Tlo - MARGIN);
  int mC = 0, aC = 0;
  #pragma unroll
  for (int i = 0; i < 16; ++i) {
    unsigned u = su[i];
    if (u > uhi) ++mC;
    else if (u >= ulo) ++aC;
  }
  int xs = mC | (aC << 16);
  #pragma unroll
  for (int off = 1; off < 64; off <<= 1) {
    int y = __shfl_up(xs, off);
    if (lane >= off) xs += y;
  }
  if (lane == 63) sred[wave] = xs;
  __syncthreads();
  int base = 0;
  for (int w = 0; w < 4; ++w)
    if (w < wave) base += sred[w];
  int tot = sred[0] + sred[1] + sred[2] + sred[3];
  int incl = base + xs;
  int mp = (incl & 0xffff) - mC;
  int ap = (incl >> 16) - aC;
  int mTot = tot & 0xffff, aTot = tot >> 16;
  const int need = TOPK - mTot;
  const bool fast = (aTot == need);  // zone exactly fills the remainder
  #pragma unroll
  for (int e = 0; e < 16; ++e) {
    unsigned u = su[e];
    int d = (e >> 2) * 1024 + tid * 4 + (e & 3);
    if (u > uhi) {
      vals[(size_t)row * TOPK + mp] = fmaxf(sortable_f32(u), 0.0f);
      idxs[(size_t)row * TOPK + mp] = d;
      ++mp;
    } else if (u >= ulo) {
      if (fast) {
        vals[(size_t)row * TOPK + mTot + ap] = fmaxf(sortable_f32(u), 0.0f);
        idxs[(size_t)row * TOPK + mTot + ap] = d;
      } else if (ap < 128) {
        ambIdx[(size_t)row * 128 + ap] = d;
      }
      ++ap;
    }
  }
  if (tid == 0) {
    rowMeta[row * 2 + 0] = mTot;
    rowMeta[row * 2 + 1] = (fast || need <= 0) ? 0 : ((aTot > 128) ? 128 : aTot);
  }
}

// ------------------------------ fp64 rescue --------------------------------

__global__ __launch_bounds__(256) void rescue(
    const float* __restrict__ x, const float* __restrict__ WT,
    const float* __restrict__ pre_bias, const float* __restrict__ latent_bias,
    const float* __restrict__ acts, const int* __restrict__ ambIdx,
    const int* __restrict__ rowMeta, float* __restrict__ vals,
    int* __restrict__ idxs) {
  const int row = blockIdx.x;
  const int m = rowMeta[row * 2 + 0];
  const int s = rowMeta[row * 2 + 1];
  const int need = TOPK - m;
  const int tid = threadIdx.x;
  if (need <= 0 || s <= 0) return;
  if (s == need) {  // residual fast path (normally resolved in classify)
    if (tid < s) {
      int d = ambIdx[(size_t)row * 128 + tid];
      float v = acts[(size_t)row * D_DIM + d];
      vals[(size_t)row * TOPK + m + tid] = fmaxf(v, 0.0f);
      idxs[(size_t)row * TOPK + m + tid] = d;
    }
    return;
  }
  __shared__ double exv[128];
  const int lane = tid & 63, wave = tid >> 6;
  const float* xr = x + (size_t)row * D_DIM;
  for (int c = wave; c < s; c += 4) {
    int d = ambIdx[(size_t)row * 128 + c];
    const float* wrow = WT + (size_t)d * D_DIM;
    double acc = 0.0;
    #pragma unroll 4
    for (int t = 0; t < 16; ++t) {
      int k0 = t * 256 + lane * 4;
      float4 xv = *(const float4*)(xr + k0);
      float4 pv = *(const float4*)(pre_bias + k0);
      float4 wv = *(const float4*)(wrow + k0);
      acc = fma((double)xv.x - (double)pv.x, (double)wv.x, acc);
      acc = fma((double)xv.y - (double)pv.y, (double)wv.y, acc);
      acc = fma((double)xv.z - (double)pv.z, (double)wv.z, acc);
      acc = fma((double)xv.w - (double)pv.w, (double)wv.w, acc);
    }
    #pragma unroll
    for (int off = 32; off; off >>= 1) acc += __shfl_down(acc, off);
    if (lane == 0) exv[c] = acc + (double)latent_bias[d];
  }
  __syncthreads();
  if (tid == 0) {
    for (int t = 0; t < need; ++t) {
      double best = -1.0e300; int besti = 1 << 30; int bestc = -1;
      for (int c = 0; c < s; ++c) {
        double v = exv[c];
        int d = ambIdx[(size_t)row * 128 + c];
        if (v > best || (v == best && d < besti)) {
          best = v; besti = d; bestc = c;
        }
      }
      vals[(size_t)row * TOPK + m + t] = fmaxf((float)best, 0.0f);
      idxs[(size_t)row * TOPK + m + t] = besti;
      exv[bestc] = -1.0e300;
    }
  }
}

// ----------------------------- reconstruct ---------------------------------

__global__ __launch_bounds__(256) void reconstruct(
    const unsigned short* __restrict__ Wd, const float* __restrict__ vals,
    const int* __restrict__ idxs, const float* __restrict__ pre_bias,
    float* __restrict__ out) {
  const int bid = blockIdx.x;
  const int cb = bid & 7, rowblk = bid >> 3;
  const int tid = threadIdx.x, lane = tid & 63, wave = tid >> 6;
  const int row = rowblk * 4 + wave;
  const int col0 = cb * 512 + lane * 8;
  __shared__ float sval[256];
  __shared__ int sidx[256];
  sval[tid] = vals[(size_t)(rowblk * 4 + (tid >> 6)) * TOPK + (tid & 63)];
  sidx[tid] = idxs[(size_t)(rowblk * 4 + (tid >> 6)) * TOPK + (tid & 63)];
  __syncthreads();
  float acc[8];
  float4 p0 = *(const float4*)(pre_bias + col0);
  float4 p1 = *(const float4*)(pre_bias + col0 + 4);
  acc[0] = p0.x; acc[1] = p0.y; acc[2] = p0.z; acc[3] = p0.w;
  acc[4] = p1.x; acc[5] = p1.y; acc[6] = p1.z; acc[7] = p1.w;
  #pragma unroll 4
  for (int k = 0; k < TOPK; ++k) {
    float v = sval[wave * 64 + k];
    int d = sidx[wave * 64 + k];
    ushort8 w = *(const ushort8*)(Wd + (size_t)d * D_DIM + col0);
    #pragma unroll
    for (int j = 0; j < 8; ++j)
      acc[j] = fmaf(v, __uint_as_float(((unsigned)w[j]) << 16), acc[j]);
  }
  float4 o0 = {acc[0], acc[1], acc[2], acc[3]};
  float4 o1 = {acc[4], acc[5], acc[6], acc[7]};
  *(float4*)(out + (size_t)row * D_DIM + col0) = o0;
  *(float4*)(out + (size_t)row * D_DIM + col0 + 4) = o1;
}

// ------------------------------- launcher ----------------------------------

extern "C" void kernel_launch(void* const* d_in, const int* in_sizes, int n_in,
                              void* d_out, int out_size, void* d_ws,
                              size_t ws_size, hipStream_t stream) {
  const float* x           = (const float*)d_in[0];
  // d_in[1] = ema_frequency_counter (unused by reference)
  const float* W_enc       = (const float*)d_in[2];
  const float* W_dec       = (const float*)d_in[3];
  const float* pre_bias    = (const float*)d_in[4];
  const float* latent_bias = (const float*)d_in[5];
  float* out = (float*)d_out;  // doubles as acts buffer, overwritten last
  char* ws = (char*)d_ws;
  size_t off = 0;
  auto alloc = [&](size_t bytes) {
    size_t o = off;
    off = (off + bytes + 255) & ~(size_t)255;
    return o;
  };
  _Float16* Xh        = (_Float16*)(ws + alloc((size_t)B_ROWS * D_DIM * 2));
  _Float16* WhT       = (_Float16*)(ws + alloc((size_t)D_DIM * D_DIM * 2));
  float* WT           = (float*)(ws + alloc((size_t)D_DIM * D_DIM * 4));
  unsigned short* Wd  = (unsigned short*)(ws + alloc((size_t)D_DIM * D_DIM * 2));
  float* vals         = (float*)(ws + alloc((size_t)B_ROWS * TOPK * 4));
  int* idxs           = (int*)(ws + alloc((size_t)B_ROWS * TOPK * 4));
  int* ambIdx         = (int*)(ws + alloc((size_t)B_ROWS * 128 * 4));
  int* rowMeta        = (int*)(ws + alloc((size_t)B_ROWS * 2 * 4));
  (void)ws_size; (void)in_sizes; (void)n_in; (void)out_size;

  // allow 128KB dynamic LDS for the GEMM (cheap, deterministic, idempotent)
  (void)hipFuncSetAttribute((const void*)gemm_f16,
                            hipFuncAttributeMaxDynamicSharedMemorySize,
                            131072);

  conv_x<<<(B_ROWS * D_DIM / 8) / 256, 256, 0, stream>>>(x, pre_bias, Xh);
  transp_w<<<dim3(D_DIM / 64, D_DIM / 64), 256, 0, stream>>>(W_enc, WhT, WT);
  conv_wd<<<((size_t)D_DIM * D_DIM / 8) / 256, 256, 0, stream>>>(W_dec, Wd);
  gemm_f16<<<(B_ROWS / 256) * (D_DIM / 256), 512, 131072, stream>>>(
      Xh, WhT, latent_bias, out);
  topk_classify<<<B_ROWS, 256, 0, stream>>>(out, vals, idxs, ambIdx, rowMeta);
  rescue<<<B_ROWS, 256, 0, stream>>>(x, WT, pre_bias, latent_bias, out,
                                     ambIdx, rowMeta, vals, idxs);
  reconstruct<<<(B_ROWS / 4) * 8, 256, 0, stream>>>(Wd, vals, idxs, pre_bias,
                                                    out);
}

// Round 8
// 1157.715 us; speedup vs baseline: 1.1413x; 1.0432x over previous
//
#include <hip/hip_runtime.h>
#include <hip/hip_bf16.h>
#include <stdint.h>

// ---------------------------------------------------------------------------
// TopKAutoEncoder forward, MI355X.
// acts = (x - pre_bias) @ W_enc + latent_bias   [16384 x 4096]
// top-64/row (exact selection vs ref), relu, @ W_dec + pre_bias.
//
// GEMM: R3 measured-best (535us): 256x256 tile, BK=32, 4-deep LDS pipeline,
// counted vmcnt(8), chunk-XOR swizzle f(r)=(r>>1)&3 (0 bank conflicts),
// XCD block swizzle, setprio.
// R8: topk_classify via single-pass LDS histogram (4096 x 0.25-wide bins)
// instead of 20-iter bitwise binary search (42 barriers -> ~6).
// fp64 rescue of ambiguous zone (fast-path resolved in classify).
// bf16 sparse reconstruct with XCD-L2-resident W_dec slabs.
// ---------------------------------------------------------------------------

typedef _Float16 half8 __attribute__((ext_vector_type(8)));
typedef float f32x4 __attribute__((ext_vector_type(4)));
typedef unsigned short ushort8 __attribute__((ext_vector_type(8)));

#define B_ROWS 16384
#define D_DIM  4096
#define TOPK   64
#define MARGIN 0.25f
#define NTILES (D_DIM / 32)

__device__ __forceinline__ void gload_lds16(const void* g, void* l) {
  __builtin_amdgcn_global_load_lds(
      (const __attribute__((address_space(1))) unsigned int*)g,
      (__attribute__((address_space(3))) unsigned int*)l, 16, 0, 0);
}

__device__ __forceinline__ unsigned short f2bf(float f) {
  unsigned u = __float_as_uint(f);
  unsigned r = (u + 0x7fffu + ((u >> 16) & 1u)) >> 16;
  return (unsigned short)r;
}

// --------------------------- conversion kernels ----------------------------

__global__ __launch_bounds__(256) void conv_x(
    const float* __restrict__ x, const float* __restrict__ pre_bias,
    _Float16* __restrict__ Xh) {
  size_t g = ((size_t)blockIdx.x * 256 + threadIdx.x) * 8;
  int col = (int)(g & (D_DIM - 1));
  float4 a = *(const float4*)(x + g);
  float4 b = *(const float4*)(x + g + 4);
  float4 p = *(const float4*)(pre_bias + col);
  float4 q = *(const float4*)(pre_bias + col + 4);
  half8 h;
  h[0] = (_Float16)(a.x - p.x); h[1] = (_Float16)(a.y - p.y);
  h[2] = (_Float16)(a.z - p.z); h[3] = (_Float16)(a.w - p.w);
  h[4] = (_Float16)(b.x - q.x); h[5] = (_Float16)(b.y - q.y);
  h[6] = (_Float16)(b.z - q.z); h[7] = (_Float16)(b.w - q.w);
  *(half8*)(Xh + g) = h;
}

// W_enc [K][N] fp32 -> WhT [N][K] fp16  AND WT [N][K] fp32 (for fp64 rescue)
__global__ __launch_bounds__(256) void transp_w(
    const float* __restrict__ W, _Float16* __restrict__ WhT,
    float* __restrict__ WT) {
  __shared__ float tile[64][65];
  int bx = blockIdx.x, by = blockIdx.y;
  int tx = threadIdx.x & 63, ty4 = threadIdx.x >> 6;
  #pragma unroll 4
  for (int i = 0; i < 16; ++i) {
    int r = ty4 * 16 + i;
    tile[r][tx] = W[(size_t)(by * 64 + r) * D_DIM + bx * 64 + tx];
  }
  __syncthreads();
  #pragma unroll 4
  for (int i = 0; i < 16; ++i) {
    int r = ty4 * 16 + i;
    float v = tile[tx][r];
    size_t o = (size_t)(bx * 64 + r) * D_DIM + by * 64 + tx;
    WT[o] = v;
    WhT[o] = (_Float16)v;
  }
}

__global__ __launch_bounds__(256) void conv_wd(
    const float* __restrict__ W, unsigned short* __restrict__ o) {
  size_t g = ((size_t)blockIdx.x * 256 + threadIdx.x) * 8;
  float4 a = *(const float4*)(W + g);
  float4 b = *(const float4*)(W + g + 4);
  ushort8 v;
  v[0] = f2bf(a.x); v[1] = f2bf(a.y); v[2] = f2bf(a.z); v[3] = f2bf(a.w);
  v[4] = f2bf(b.x); v[5] = f2bf(b.y); v[6] = f2bf(b.z); v[7] = f2bf(b.w);
  *(ushort8*)(o + g) = v;
}

// ------------------------------- fp16 GEMM (R3 verbatim) -------------------

#define TILE_BODY(T, VMSTR)                                                    \
  do {                                                                         \
    asm volatile("s_waitcnt " VMSTR ::: "memory");                             \
    __builtin_amdgcn_s_barrier();                                              \
    asm volatile("" ::: "memory");                                             \
    const int tt3 = (T) + 3;                                                   \
    if (tt3 < NTILES) {                                                        \
      const int bo = (tt3 & 3) * 8192;                                         \
      const int kk = tt3 * 32;                                                 \
      gload_lds16(aSrc0 + kk, AsB + bo + dst0);                                \
      gload_lds16(aSrc1 + kk, AsB + bo + dst1);                                \
    }                                                                          \
    {                                                                          \
      const int ab = ((T) & 3) * 8192;                                         \
      half8 bf[4], af[4];                                                      \
      _Pragma("unroll") for (int nj = 0; nj < 4; ++nj)                         \
          bf[nj] = *(const half8*)(BsB + ab + bBase + nj * 512);               \
      _Pragma("unroll") for (int mi = 0; mi < 4; ++mi)                         \
          af[mi] = *(const half8*)(AsB + ab + aBase + mi * 512);               \
      __builtin_amdgcn_s_setprio(1);                                           \
      _Pragma("unroll") for (int mi = 0; mi < 4; ++mi)                         \
          _Pragma("unroll") for (int nj = 0; nj < 4; ++nj)                     \
          acc[mi][nj] = __builtin_amdgcn_mfma_f32_16x16x32_f16(                \
              af[mi], bf[nj], acc[mi][nj], 0, 0, 0);                           \
      __builtin_amdgcn_s_setprio(0);                                           \
      if (tt3 < NTILES) {                                                      \
        const int bo = (tt3 & 3) * 8192;                                       \
        const int kk = tt3 * 32;                                               \
        gload_lds16(bSrc0 + kk, BsB + bo + dst0);                              \
        gload_lds16(bSrc1 + kk, BsB + bo + dst1);                              \
      }                                                                        \
      _Pragma("unroll") for (int mi = 0; mi < 4; ++mi)                         \
          af[mi] = *(const half8*)(AsB + ab + aBase + (mi + 4) * 512);         \
      __builtin_amdgcn_s_setprio(1);                                           \
      _Pragma("unroll") for (int mi = 0; mi < 4; ++mi)                         \
          _Pragma("unroll") for (int nj = 0; nj < 4; ++nj)                     \
          acc[mi + 4][nj] = __builtin_amdgcn_mfma_f32_16x16x32_f16(            \
              af2[mi], bf[nj], acc[mi + 4][nj], 0, 0, 0);                      \
      __builtin_amdgcn_s_setprio(0);                                           \
    }                                                                          \
  } while (0)

// NOTE: af2 in the second cluster is af (renamed) -- see corrected macro below.
#undef TILE_BODY
#define TILE_BODY(T, VMSTR)                                                    \
  do {                                                                         \
    asm volatile("s_waitcnt " VMSTR ::: "memory");                             \
    __builtin_amdgcn_s_barrier();                                              \
    asm volatile("" ::: "memory");                                             \
    const int tt3 = (T) + 3;                                                   \
    if (tt3 < NTILES) {                                                        \
      const int bo = (tt3 & 3) * 8192;                                         \
      const int kk = tt3 * 32;                                                 \
      gload_lds16(aSrc0 + kk, AsB + bo + dst0);                                \
      gload_lds16(aSrc1 + kk, AsB + bo + dst1);                                \
    }                                                                          \
    {                                                                          \
      const int ab = ((T) & 3) * 8192;                                         \
      half8 bf[4], af[4];                                                      \
      _Pragma("unroll") for (int nj = 0; nj < 4; ++nj)                         \
          bf[nj] = *(const half8*)(BsB + ab + bBase + nj * 512);               \
      _Pragma("unroll") for (int mi = 0; mi < 4; ++mi)                         \
          af[mi] = *(const half8*)(AsB + ab + aBase + mi * 512);               \
      __builtin_amdgcn_s_setprio(1);                                           \
      _Pragma("unroll") for (int mi = 0; mi < 4; ++mi)                         \
          _Pragma("unroll") for (int nj = 0; nj < 4; ++nj)                     \
          acc[mi][nj] = __builtin_amdgcn_mfma_f32_16x16x32_f16(                \
              af[mi], bf[nj], acc[mi][nj], 0, 0, 0);                           \
      __builtin_amdgcn_s_setprio(0);                                           \
      if (tt3 < NTILES) {                                                      \
        const int bo = (tt3 & 3) * 8192;                                       \
        const int kk = tt3 * 32;                                               \
        gload_lds16(bSrc0 + kk, BsB + bo + dst0);                              \
        gload_lds16(bSrc1 + kk, BsB + bo + dst1);                              \
      }                                                                        \
      _Pragma("unroll") for (int mi = 0; mi < 4; ++mi)                         \
          af[mi] = *(const half8*)(AsB + ab + aBase + (mi + 4) * 512);         \
      __builtin_amdgcn_s_setprio(1);                                           \
      _Pragma("unroll") for (int mi = 0; mi < 4; ++mi)                         \
          _Pragma("unroll") for (int nj = 0; nj < 4; ++nj)                     \
          acc[mi + 4][nj] = __builtin_amdgcn_mfma_f32_16x16x32_f16(            \
              af[mi], bf[nj], acc[mi + 4][nj], 0, 0, 0);                       \
      __builtin_amdgcn_s_setprio(0);                                           \
    }                                                                          \
  } while (0)

__global__ __launch_bounds__(512, 2) void gemm_f16(
    const _Float16* __restrict__ A, const _Float16* __restrict__ Bt,
    const float* __restrict__ latent_bias, float* __restrict__ C) {
  extern __shared__ _Float16 ldsbuf[];
  _Float16* AsB = ldsbuf;            // 4 bufs x 8192 halves (256x32)
  _Float16* BsB = ldsbuf + 4 * 8192;

  const int tid = threadIdx.x;
  const int lane = tid & 63, wave = tid >> 6;
  const int wr = wave >> 2, wc = wave & 3;

  int bid = blockIdx.x;
  int swz = (bid & 7) * (1024 >> 3) + (bid >> 3);
  const int bmBase = (swz >> 4) * 256;
  const int bnBase = (swz & 15) * 256;

  const int i0 = tid, i1 = 512 + tid;
  const int s0 = i0 ^ ((i0 >> 3) & 3), s1 = i1 ^ ((i1 >> 3) & 3);
  const _Float16* aSrc0 = A + (size_t)(bmBase + (s0 >> 2)) * D_DIM + (s0 & 3) * 8;
  const _Float16* aSrc1 = A + (size_t)(bmBase + (s1 >> 2)) * D_DIM + (s1 & 3) * 8;
  const _Float16* bSrc0 = Bt + (size_t)(bnBase + (s0 >> 2)) * D_DIM + (s0 & 3) * 8;
  const _Float16* bSrc1 = Bt + (size_t)(bnBase + (s1 >> 2)) * D_DIM + (s1 & 3) * 8;
  const int dst0 = i0 * 8, dst1 = i1 * 8;

  const int fr = lane & 15, c4 = lane >> 4;
  const int swzc = (c4 ^ ((fr >> 1) & 3)) * 8;
  const int aBase = (wr * 128 + fr) * 32 + swzc;
  const int bBase = (wc * 64 + fr) * 32 + swzc;

  f32x4 acc[8][4];
  #pragma unroll
  for (int i = 0; i < 8; ++i)
    #pragma unroll
    for (int j = 0; j < 4; ++j) acc[i][j] = f32x4{0.f, 0.f, 0.f, 0.f};

  #pragma unroll
  for (int tt = 0; tt < 3; ++tt) {
    const int bo = tt * 8192, kk = tt * 32;
    gload_lds16(aSrc0 + kk, AsB + bo + dst0);
    gload_lds16(aSrc1 + kk, AsB + bo + dst1);
    gload_lds16(bSrc0 + kk, BsB + bo + dst0);
    gload_lds16(bSrc1 + kk, BsB + bo + dst1);
  }

  for (int t = 0; t < NTILES - 2; ++t) TILE_BODY(t, "vmcnt(8)");
  TILE_BODY(NTILES - 2, "vmcnt(4)");
  TILE_BODY(NTILES - 1, "vmcnt(0)");

  const int crow0 = bmBase + wr * 128 + c4 * 4;
  const int ccol0 = bnBase + wc * 64 + fr;
  #pragma unroll
  for (int mi = 0; mi < 8; ++mi)
    #pragma unroll
    for (int nj = 0; nj < 4; ++nj) {
      int col = ccol0 + nj * 16;
      float lb = latent_bias[col];
      #pragma unroll
      for (int r = 0; r < 4; ++r)
        C[(size_t)(crow0 + mi * 16 + r) * D_DIM + col] = acc[mi][nj][r] + lb;
    }
}

// --------------------------- top-k classify (R8: histogram) ----------------
// Single pass: 4096 bins of width 0.25 over [-512,512). Suffix-count scan
// finds b* = largest bin with count(values >= edge(b*)) >= 64, so
// T64_approx in [Tlo, Thi) with Thi-Tlo = 0.25. Members: v > Thi+MARGIN
// (provably in exact top-64, provably < 64 of them). Zone:
// [Tlo-MARGIN, Thi+MARGIN]. Fast path: zone == need -> emit directly.

__global__ __launch_bounds__(256) void topk_classify(
    const float* __restrict__ acts, float* __restrict__ vals,
    int* __restrict__ idxs, int* __restrict__ ambIdx,
    int* __restrict__ rowMeta) {
  const int row = blockIdx.x;
  const int tid = threadIdx.x;
  const int lane = tid & 63, wave = tid >> 6;
  __shared__ int hist[4096];
  __shared__ int sred[8];
  const float* arow = acts + (size_t)row * D_DIM;
  float fv[16];
  #pragma unroll
  for (int i = 0; i < 4; ++i) {
    float4 a = *(const float4*)(arow + i * 1024 + tid * 4);
    fv[4 * i + 0] = a.x; fv[4 * i + 1] = a.y;
    fv[4 * i + 2] = a.z; fv[4 * i + 3] = a.w;
  }
  #pragma unroll
  for (int i = 0; i < 16; ++i) hist[tid * 16 + i] = 0;
  __syncthreads();
  #pragma unroll
  for (int e = 0; e < 16; ++e) {
    int b = (int)((fv[e] + 512.0f) * 4.0f);
    b = b < 0 ? 0 : (b > 4095 ? 4095 : b);
    atomicAdd(&hist[b], 1);
  }
  __syncthreads();
  // local suffix over this thread's 16 contiguous bins
  int loc[16];
  int s = 0;
  #pragma unroll
  for (int i = 15; i >= 0; --i) { s += hist[tid * 16 + i]; loc[i] = s; }
  // inclusive suffix scan of per-thread totals within wave
  int x = s;
  #pragma unroll
  for (int off = 1; off < 64; off <<= 1) {
    int y = __shfl_down(x, off);
    if (lane + off < 64) x += y;
  }
  if (lane == 0) sred[wave] = x;  // wave total
  __syncthreads();
  int after = 0;
  for (int w = wave + 1; w < 4; ++w) after += sred[w];
  const int sufAfter = (x - s) + after;  // sum over threads strictly after tid
  // largest bin with suffix >= TOPK (monotone -> block max of candidates)
  int cand = -1;
  #pragma unroll
  for (int i = 0; i < 16; ++i)
    if (loc[i] + sufAfter >= TOPK) cand = tid * 16 + i;
  #pragma unroll
  for (int off = 32; off; off >>= 1) {
    int y = __shfl_down(cand, off);
    cand = y > cand ? y : cand;
  }
  if (lane == 0) sred[4 + wave] = cand;
  __syncthreads();
  int b0 = sred[4] > sred[5] ? sred[4] : sred[5];
  int b1 = sred[6] > sred[7] ? sred[6] : sred[7];
  const int bstar = b0 > b1 ? b0 : b1;  // exists: suffix(0)=4096>=64
  const float Tlo = (bstar == 0) ? -1e30f : (bstar * 0.25f - 512.0f);
  const float Thi = (bstar >= 4095) ? 1e30f : ((bstar + 1) * 0.25f - 512.0f);
  const float vhi = Thi + MARGIN;
  const float vlo = Tlo - MARGIN;
  int mC = 0, aC = 0;
  #pragma unroll
  for (int i = 0; i < 16; ++i) {
    float v = fv[i];
    if (v > vhi) ++mC;
    else if (v >= vlo) ++aC;
  }
  int xs = mC | (aC << 16);
  #pragma unroll
  for (int off = 1; off < 64; off <<= 1) {
    int y = __shfl_up(xs, off);
    if (lane >= off) xs += y;
  }
  if (lane == 63) sred[wave] = xs;
  __syncthreads();
  int base = 0;
  for (int w = 0; w < 4; ++w)
    if (w < wave) base += sred[w];
  int tot = sred[0] + sred[1] + sred[2] + sred[3];
  int incl = base + xs;
  int mp = (incl & 0xffff) - mC;
  int ap = (incl >> 16) - aC;
  int mTot = tot & 0xffff, aTot = tot >> 16;
  const int need = TOPK - mTot;
  const bool fast = (aTot == need);  // zone exactly fills the remainder
  #pragma unroll
  for (int e = 0; e < 16; ++e) {
    float v = fv[e];
    int d = (e >> 2) * 1024 + tid * 4 + (e & 3);
    if (v > vhi) {
      vals[(size_t)row * TOPK + mp] = fmaxf(v, 0.0f);
      idxs[(size_t)row * TOPK + mp] = d;
      ++mp;
    } else if (v >= vlo) {
      if (fast) {
        vals[(size_t)row * TOPK + mTot + ap] = fmaxf(v, 0.0f);
        idxs[(size_t)row * TOPK + mTot + ap] = d;
      } else if (ap < 128) {
        ambIdx[(size_t)row * 128 + ap] = d;
      }
      ++ap;
    }
  }
  if (tid == 0) {
    rowMeta[row * 2 + 0] = mTot;
    rowMeta[row * 2 + 1] = (fast || need <= 0) ? 0 : ((aTot > 128) ? 128 : aTot);
  }
}

// ------------------------------ fp64 rescue --------------------------------

__global__ __launch_bounds__(256) void rescue(
    const float* __restrict__ x, const float* __restrict__ WT,
    const float* __restrict__ pre_bias, const float* __restrict__ latent_bias,
    const float* __restrict__ acts, const int* __restrict__ ambIdx,
    const int* __restrict__ rowMeta, float* __restrict__ vals,
    int* __restrict__ idxs) {
  const int row = blockIdx.x;
  const int m = rowMeta[row * 2 + 0];
  const int s = rowMeta[row * 2 + 1];
  const int need = TOPK - m;
  const int tid = threadIdx.x;
  if (need <= 0 || s <= 0) return;
  if (s == need) {  // residual fast path (normally resolved in classify)
    if (tid < s) {
      int d = ambIdx[(size_t)row * 128 + tid];
      float v = acts[(size_t)row * D_DIM + d];
      vals[(size_t)row * TOPK + m + tid] = fmaxf(v, 0.0f);
      idxs[(size_t)row * TOPK + m + tid] = d;
    }
    return;
  }
  __shared__ double exv[128];
  const int lane = tid & 63, wave = tid >> 6;
  const float* xr = x + (size_t)row * D_DIM;
  for (int c = wave; c < s; c += 4) {
    int d = ambIdx[(size_t)row * 128 + c];
    const float* wrow = WT + (size_t)d * D_DIM;
    double acc = 0.0;
    #pragma unroll 4
    for (int t = 0; t < 16; ++t) {
      int k0 = t * 256 + lane * 4;
      float4 xv = *(const float4*)(xr + k0);
      float4 pv = *(const float4*)(pre_bias + k0);
      float4 wv = *(const float4*)(wrow + k0);
      acc = fma((double)xv.x - (double)pv.x, (double)wv.x, acc);
      acc = fma((double)xv.y - (double)pv.y, (double)wv.y, acc);
      acc = fma((double)xv.z - (double)pv.z, (double)wv.z, acc);
      acc = fma((double)xv.w - (double)pv.w, (double)wv.w, acc);
    }
    #pragma unroll
    for (int off = 32; off; off >>= 1) acc += __shfl_down(acc, off);
    if (lane == 0) exv[c] = acc + (double)latent_bias[d];
  }
  __syncthreads();
  if (tid == 0) {
    for (int t = 0; t < need; ++t) {
      double best = -1.0e300; int besti = 1 << 30; int bestc = -1;
      for (int c = 0; c < s; ++c) {
        double v = exv[c];
        int d = ambIdx[(size_t)row * 128 + c];
        if (v > best || (v == best && d < besti)) {
          best = v; besti = d; bestc = c;
        }
      }
      vals[(size_t)row * TOPK + m + t] = fmaxf((float)best, 0.0f);
      idxs[(size_t)row * TOPK + m + t] = besti;
      exv[bestc] = -1.0e300;
    }
  }
}

// ----------------------------- reconstruct ---------------------------------

__global__ __launch_bounds__(256) void reconstruct(
    const unsigned short* __restrict__ Wd, const float* __restrict__ vals,
    const int* __restrict__ idxs, const float* __restrict__ pre_bias,
    float* __restrict__ out) {
  const int bid = blockIdx.x;
  const int cb = bid & 7, rowblk = bid >> 3;
  const int tid = threadIdx.x, lane = tid & 63, wave = tid >> 6;
  const int row = rowblk * 4 + wave;
  const int col0 = cb * 512 + lane * 8;
  __shared__ float sval[256];
  __shared__ int sidx[256];
  sval[tid] = vals[(size_t)(rowblk * 4 + (tid >> 6)) * TOPK + (tid & 63)];
  sidx[tid] = idxs[(size_t)(rowblk * 4 + (tid >> 6)) * TOPK + (tid & 63)];
  __syncthreads();
  float acc[8];
  float4 p0 = *(const float4*)(pre_bias + col0);
  float4 p1 = *(const float4*)(pre_bias + col0 + 4);
  acc[0] = p0.x; acc[1] = p0.y; acc[2] = p0.z; acc[3] = p0.w;
  acc[4] = p1.x; acc[5] = p1.y; acc[6] = p1.z; acc[7] = p1.w;
  #pragma unroll 4
  for (int k = 0; k < TOPK; ++k) {
    float v = sval[wave * 64 + k];
    int d = sidx[wave * 64 + k];
    ushort8 w = *(const ushort8*)(Wd + (size_t)d * D_DIM + col0);
    #pragma unroll
    for (int j = 0; j < 8; ++j)
      acc[j] = fmaf(v, __uint_as_float(((unsigned)w[j]) << 16), acc[j]);
  }
  float4 o0 = {acc[0], acc[1], acc[2], acc[3]};
  float4 o1 = {acc[4], acc[5], acc[6], acc[7]};
  *(float4*)(out + (size_t)row * D_DIM + col0) = o0;
  *(float4*)(out + (size_t)row * D_DIM + col0 + 4) = o1;
}

// ------------------------------- launcher ----------------------------------

extern "C" void kernel_launch(void* const* d_in, const int* in_sizes, int n_in,
                              void* d_out, int out_size, void* d_ws,
                              size_t ws_size, hipStream_t stream) {
  const float* x           = (const float*)d_in[0];
  // d_in[1] = ema_frequency_counter (unused by reference)
  const float* W_enc       = (const float*)d_in[2];
  const float* W_dec       = (const float*)d_in[3];
  const float* pre_bias    = (const float*)d_in[4];
  const float* latent_bias = (const float*)d_in[5];
  float* out = (float*)d_out;  // doubles as acts buffer, overwritten last
  char* ws = (char*)d_ws;
  size_t off = 0;
  auto alloc = [&](size_t bytes) {
    size_t o = off;
    off = (off + bytes + 255) & ~(size_t)255;
    return o;
  };
  _Float16* Xh        = (_Float16*)(ws + alloc((size_t)B_ROWS * D_DIM * 2));
  _Float16* WhT       = (_Float16*)(ws + alloc((size_t)D_DIM * D_DIM * 2));
  float* WT           = (float*)(ws + alloc((size_t)D_DIM * D_DIM * 4));
  unsigned short* Wd  = (unsigned short*)(ws + alloc((size_t)D_DIM * D_DIM * 2));
  float* vals         = (float*)(ws + alloc((size_t)B_ROWS * TOPK * 4));
  int* idxs           = (int*)(ws + alloc((size_t)B_ROWS * TOPK * 4));
  int* ambIdx         = (int*)(ws + alloc((size_t)B_ROWS * 128 * 4));
  int* rowMeta        = (int*)(ws + alloc((size_t)B_ROWS * 2 * 4));
  (void)ws_size; (void)in_sizes; (void)n_in; (void)out_size;

  // allow 128KB dynamic LDS for the GEMM (cheap, deterministic, idempotent)
  (void)hipFuncSetAttribute((const void*)gemm_f16,
                            hipFuncAttributeMaxDynamicSharedMemorySize,
                            131072);

  conv_x<<<(B_ROWS * D_DIM / 8) / 256, 256, 0, stream>>>(x, pre_bias, Xh);
  transp_w<<<dim3(D_DIM / 64, D_DIM / 64), 256, 0, stream>>>(W_enc, WhT, WT);
  conv_wd<<<((size_t)D_DIM * D_DIM / 8) / 256, 256, 0, stream>>>(W_dec, Wd);
  gemm_f16<<<(B_ROWS / 256) * (D_DIM / 256), 512, 131072, stream>>>(
      Xh, WhT, latent_bias, out);
  topk_classify<<<B_ROWS, 256, 0, stream>>>(out, vals, idxs, ambIdx, rowMeta);
  rescue<<<B_ROWS, 256, 0, stream>>>(x, WT, pre_bias, latent_bias, out,
                                     ambIdx, rowMeta, vals, idxs);
  reconstruct<<<(B_ROWS / 4) * 8, 256, 0, stream>>>(Wd, vals, idxs, pre_bias,
                                                    out);
}